// Round 1
// baseline (1300.972 us; speedup 1.0000x reference)
//
#include <hip/hip_runtime.h>
#include <cstddef>

#define T_ 64
#define B_ 256
#define D_ 512
#define L_ 50
#define A_ 18
#define H_ 32

// ---------------- LDS layout for seq kernel (floats) ----------------
constexpr int OW_C1  = 0;                    // W_comb[:, 0:512]  [32][513] (padded)
constexpr int OW_A2  = OW_C1 + 32 * 513;     // W_attn[:, 512:544] transposed [32][50]
constexpr int OW_IH  = OW_A2 + 1600;         // W_ih transposed [32][128]
constexpr int OW_HH  = OW_IH + 4096;         // W_hh transposed [32][128]
constexpr int OW_MID = OW_HH + 4096;         // W_mid transposed [32][64]
constexpr int OW_OUT = OW_MID + 2048;        // W_out transposed [64][18]
constexpr int OBG    = OW_OUT + 1152;        // b_ih + b_hh [128]
constexpr int OBM    = OBG + 128;            // b_mid [64]
constexpr int OBO    = OBM + 64;             // b_out [18] (+pad)
constexpr int OAPP   = OBO + 20;             // applied [512]
constexpr int OSW    = OAPP + 512;           // softmax weights [50] (+pad)
constexpr int OSX    = OSW + 52;             // x [32]
constexpr int OSH    = OSX + 32;             // h [32]
constexpr int OSC    = OSH + 32;             // c [32]
constexpr int OG     = OSC + 32;             // gates [128]
constexpr int OMID   = OG + 128;             // mid [64]
constexpr int SMEM_FLOATS = OMID + 64;       // = 30472 floats = 121888 bytes

__device__ __forceinline__ float sigf(float x) { return 1.f / (1.f + expf(-x)); }

// ---------------------------------------------------------------------------
// Kernel 1: precompute, for every row r = t*B + b:
//   lc[r,l] = state[r,:] . W_attn[l, 0:512] + b_attn[l]        (l < 50)
//   cc[r,h] = state[r,:] . W_comb[h, 512:1024] + b_comb[h]     (h < 32)
// 6 rows per block, thread = (row, j) with j in [0,82).
// ---------------------------------------------------------------------------
__global__ __launch_bounds__(512) void precompute_kernel(
    const float* __restrict__ state,
    const float* __restrict__ W_attn, const float* __restrict__ b_attn,
    const float* __restrict__ W_comb, const float* __restrict__ b_comb,
    float* __restrict__ lc, float* __restrict__ cc) {
  __shared__ float scur[6 * 512];
  const int r0 = blockIdx.x * 6;
  for (int f = threadIdx.x; f < 6 * 512; f += 512) {
    int r = f >> 9, cidx = f & 511;
    int row = r0 + r;
    scur[f] = (row < T_ * B_) ? state[(size_t)row * D_ + cidx] : 0.f;
  }
  __syncthreads();
  const int i = threadIdx.x;
  if (i < 492) {
    int r = i / 82, j = i % 82;
    int row = r0 + r;
    if (row < T_ * B_) {
      const float* wrow = (j < 50) ? (W_attn + (size_t)j * (D_ + H_))
                                   : (W_comb + (size_t)(j - 50) * (2 * D_) + D_);
      const float4* w4 = reinterpret_cast<const float4*>(wrow);
      const float4* c4 = reinterpret_cast<const float4*>(scur + r * 512);
      float acc = 0.f;
#pragma unroll 8
      for (int k = 0; k < 128; ++k) {
        float4 a = c4[k], w = w4[k];
        acc += a.x * w.x + a.y * w.y + a.z * w.z + a.w * w.w;
      }
      if (j < 50) lc[(size_t)row * L_ + j] = acc + b_attn[j];
      else        cc[(size_t)row * H_ + (j - 50)] = acc + b_comb[j - 50];
    }
  }
}

// ---------------------------------------------------------------------------
// Kernel 2: sequential scan. One block per batch element b (256 blocks, 512 thr).
// ---------------------------------------------------------------------------
__global__ __launch_bounds__(512) void seq_kernel(
    const float* __restrict__ demo,
    const float* __restrict__ h0, const float* __restrict__ c0,
    const float* __restrict__ W_attn, const float* __restrict__ W_comb,
    const float* __restrict__ W_ih, const float* __restrict__ b_ih,
    const float* __restrict__ W_hh, const float* __restrict__ b_hh,
    const float* __restrict__ W_mid, const float* __restrict__ b_mid,
    const float* __restrict__ W_out, const float* __restrict__ b_out,
    const float* __restrict__ lc, const float* __restrict__ cc,
    float* __restrict__ out) {
  extern __shared__ float sm[];
  const int b = blockIdx.x;
  const int tid = threadIdx.x;

  // ---- stage weights into LDS (once) ----
  for (int f = tid; f < 32 * 512; f += 512) {        // W_comb[:, 0:512], padded rows
    int h = f >> 9, d = f & 511;
    sm[OW_C1 + h * 513 + d] = W_comb[(size_t)h * (2 * D_) + d];
  }
  for (int f = tid; f < 32 * 50; f += 512) {         // W_attn[:, 512:] transposed
    int k = f / 50, l = f % 50;
    sm[OW_A2 + f] = W_attn[(size_t)l * (D_ + H_) + D_ + k];
  }
  for (int f = tid; f < 32 * 128; f += 512) {        // W_ih^T
    int k = f >> 7, j = f & 127;
    sm[OW_IH + f] = W_ih[(size_t)j * H_ + k];
  }
  for (int f = tid; f < 32 * 128; f += 512) {        // W_hh^T
    int k = f >> 7, j = f & 127;
    sm[OW_HH + f] = W_hh[(size_t)j * H_ + k];
  }
  for (int f = tid; f < 32 * 64; f += 512) {         // W_mid^T
    int k = f >> 6, m = f & 63;
    sm[OW_MID + f] = W_mid[(size_t)m * H_ + k];
  }
  for (int f = tid; f < 64 * 18; f += 512) {         // W_out^T
    int k = f / 18, a = f % 18;
    sm[OW_OUT + f] = W_out[(size_t)a * (2 * H_) + k];
  }
  if (tid < 128) sm[OBG + tid] = b_ih[tid] + b_hh[tid];
  if (tid < 64)  sm[OBM + tid] = b_mid[tid];
  if (tid < 18)  sm[OBO + tid] = b_out[tid];
  if (tid < 32) {
    sm[OSH + tid] = h0[(size_t)b * H_ + tid];
    sm[OSC + tid] = c0[(size_t)b * H_ + tid];
  }
  __syncthreads();

  for (int t = 0; t < T_; ++t) {
    const size_t row = (size_t)t * B_ + b;

    // issue small loads first (lc/cc), then the 50 demo prefetch loads
    float lcv = 0.f;
    if (tid < 50) lcv = lc[row * L_ + tid];
    const float ccv = cc[row * H_ + (tid >> 4)];

    const float* dbase = demo + row * (L_ * D_) + tid;
    float vd[L_];
#pragma unroll
    for (int l = 0; l < L_; ++l) vd[l] = dbase[(size_t)l * D_];

    // ---- logits + softmax (wave 0) ----
    if (tid < 64) {
      float logit = -INFINITY;
      if (tid < 50) {
        float acc = lcv;
#pragma unroll
        for (int k = 0; k < 32; ++k) acc += sm[OSH + k] * sm[OW_A2 + k * 50 + tid];
        logit = acc;
      }
      float mx = logit;
#pragma unroll
      for (int off = 32; off; off >>= 1) mx = fmaxf(mx, __shfl_xor(mx, off, 64));
      float e = (tid < 50) ? expf(logit - mx) : 0.f;
      float ssum = e;
#pragma unroll
      for (int off = 32; off; off >>= 1) ssum += __shfl_xor(ssum, off, 64);
      if (tid < 50) sm[OSW + tid] = e / ssum;
    }
    __syncthreads();

    // ---- applied[d] = sum_l w[l] * demo[t,b,l,d] ----
    {
      float acc = 0.f;
#pragma unroll
      for (int l = 0; l < L_; ++l) acc += sm[OSW + l] * vd[l];
      sm[OAPP + tid] = acc;
    }
    __syncthreads();

    // ---- x[h] = relu(applied . Wc1[h,:] + cc) ; 16 lanes per h ----
    {
      int h = tid >> 4, s = tid & 15;
      const float* wrow = sm + OW_C1 + h * 513;
      float part = 0.f;
#pragma unroll
      for (int i2 = 0; i2 < 32; ++i2) {
        int d = s + (i2 << 4);
        part += sm[OAPP + d] * wrow[d];
      }
      part += __shfl_xor(part, 8, 64);
      part += __shfl_xor(part, 4, 64);
      part += __shfl_xor(part, 2, 64);
      part += __shfl_xor(part, 1, 64);
      if (s == 0) sm[OSX + h] = fmaxf(part + ccv, 0.f);
    }
    __syncthreads();

    // ---- gates[j] = bg[j] + x.Wih[j,:] + h.Whh[j,:] (threads 0..127) ----
    if (tid < 128) {
      float g = sm[OBG + tid];
#pragma unroll
      for (int k = 0; k < 32; ++k)
        g += sm[OSX + k] * sm[OW_IH + k * 128 + tid] +
             sm[OSH + k] * sm[OW_HH + k * 128 + tid];
      sm[OG + tid] = g;
    }
    __syncthreads();

    // ---- LSTM cell + mid + q : all wave 0, same-wave LDS program order ----
    if (tid < 32) {
      float ig = sigf(sm[OG + tid]);
      float fg = sigf(sm[OG + 32 + tid]);
      float gg = tanhf(sm[OG + 64 + tid]);
      float og = sigf(sm[OG + 96 + tid]);
      float cn = fg * sm[OSC + tid] + ig * gg;
      sm[OSC + tid] = cn;
      sm[OSH + tid] = og * tanhf(cn);
    }
    if (tid < 64) {
      float a2 = sm[OBM + tid];
#pragma unroll
      for (int k = 0; k < 32; ++k) a2 += sm[OSH + k] * sm[OW_MID + k * 64 + tid];
      sm[OMID + tid] = a2;
    }
    if (tid < 18) {
      float a3 = sm[OBO + tid];
#pragma unroll
      for (int k = 0; k < 64; ++k) a3 += sm[OMID + k] * sm[OW_OUT + k * 18 + tid];
      out[row * A_ + tid] = a3;
    }
    __syncthreads();
  }

  // ---- final h, c ----
  if (tid < 32) {
    out[(size_t)T_ * B_ * A_ + (size_t)b * H_ + tid] = sm[OSH + tid];
    out[(size_t)T_ * B_ * A_ + (size_t)B_ * H_ + (size_t)b * H_ + tid] = sm[OSC + tid];
  }
}

extern "C" void kernel_launch(void* const* d_in, const int* in_sizes, int n_in,
                              void* d_out, int out_size, void* d_ws, size_t ws_size,
                              hipStream_t stream) {
  const float* state  = (const float*)d_in[0];
  const float* demo   = (const float*)d_in[1];
  const float* h0     = (const float*)d_in[2];
  const float* c0     = (const float*)d_in[3];
  const float* W_attn = (const float*)d_in[4];
  const float* b_attn = (const float*)d_in[5];
  const float* W_comb = (const float*)d_in[6];
  const float* b_comb = (const float*)d_in[7];
  const float* W_ih   = (const float*)d_in[8];
  const float* b_ih   = (const float*)d_in[9];
  const float* W_hh   = (const float*)d_in[10];
  const float* b_hh   = (const float*)d_in[11];
  const float* W_mid  = (const float*)d_in[12];
  const float* b_mid  = (const float*)d_in[13];
  const float* W_out  = (const float*)d_in[14];
  const float* b_out  = (const float*)d_in[15];
  float* out = (float*)d_out;

  float* lc = (float*)d_ws;                       // [T*B, 50]
  float* cc = lc + (size_t)T_ * B_ * L_;          // [T*B, 32]

  // precompute lc/cc
  int nrow = T_ * B_;
  int nblk = (nrow + 5) / 6;
  precompute_kernel<<<dim3(nblk), dim3(512), 0, stream>>>(
      state, W_attn, b_attn, W_comb, b_comb, lc, cc);

  // sequential scan, one block per batch element
  constexpr int smem_bytes = SMEM_FLOATS * 4;
  (void)hipFuncSetAttribute(reinterpret_cast<const void*>(seq_kernel),
                            hipFuncAttributeMaxDynamicSharedMemorySize, smem_bytes);
  seq_kernel<<<dim3(B_), dim3(512), smem_bytes, stream>>>(
      demo, h0, c0, W_attn, W_comb, W_ih, b_ih, W_hh, b_hh,
      W_mid, b_mid, W_out, b_out, lc, cc, out);
}

// Round 2
// 1113.767 us; speedup vs baseline: 1.1681x; 1.1681x over previous
//
#include <hip/hip_runtime.h>
#include <cstddef>
#include <cstdint>

#define T_ 64
#define B_ 256
#define D_ 512
#define L_ 50
#define A_ 18
#define H_ 32

typedef __attribute__((ext_vector_type(8))) short short8;
typedef __attribute__((ext_vector_type(4))) float f32x4;

// ---- workspace float offsets ----
constexpr size_t WS_LC = 0;                   // [16384*50]
constexpr size_t WS_CC = 819200;              // [16384*32]
constexpr size_t WS_WQ = WS_CC + 524288;      // [18*32] folded W_out@W_mid
constexpr size_t WS_BQ = WS_WQ + 576;         // [18] folded bias
constexpr size_t WS_DP = WS_WQ + 640;         // [819200*32] dp = demo @ Wc1^T

__device__ __forceinline__ float sigf(float x) { return 1.f / (1.f + expf(-x)); }

__device__ __forceinline__ short f2bf_rne(float f) {
  unsigned u = __float_as_uint(f);
  return (short)((u + 0x7fffu + ((u >> 16) & 1u)) >> 16);
}
__device__ __forceinline__ float bcast(float v, int l) {
  return __int_as_float(__builtin_amdgcn_readlane(__float_as_int(v), l));
}
__device__ __forceinline__ void glds16(const float* g, float* l) {
  __builtin_amdgcn_global_load_lds((const __attribute__((address_space(1))) unsigned*)g,
                                   (__attribute__((address_space(3))) unsigned*)l, 16, 0, 0);
}
__device__ __forceinline__ void glds4(const float* g, float* l) {
  __builtin_amdgcn_global_load_lds((const __attribute__((address_space(1))) unsigned*)g,
                                   (__attribute__((address_space(3))) unsigned*)l, 4, 0, 0);
}

// ---------------------------------------------------------------------------
// lc[r,l] = state[r,:]·W_attn[l,:512] + b_attn[l]   (l<50)
// cc[r,h] = state[r,:]·W_comb[h,512:] + b_comb[h]   (h<32)
// 24 rows per block; each thread reuses its weight row over 4 rows.
// ---------------------------------------------------------------------------
__global__ __launch_bounds__(512) void precompute2(
    const float* __restrict__ state,
    const float* __restrict__ W_attn, const float* __restrict__ b_attn,
    const float* __restrict__ W_comb, const float* __restrict__ b_comb,
    float* __restrict__ lc, float* __restrict__ cc) {
  const int tid = threadIdx.x;
  if (tid >= 492) return;
  const int j = tid % 82, rg = tid / 82;
  const int r0 = blockIdx.x * 24 + rg * 4;
  const float* wrow = (j < 50) ? (W_attn + (size_t)j * 544)
                               : (W_comb + (size_t)(j - 50) * 1024 + 512);
  const float bias = (j < 50) ? b_attn[j] : b_comb[j - 50];
  const f32x4* w4 = (const f32x4*)wrow;
  const f32x4* s4 = (const f32x4*)state;
  int re[4];
#pragma unroll
  for (int rr = 0; rr < 4; ++rr) re[rr] = min(r0 + rr, 16383);
  float acc[4] = {0.f, 0.f, 0.f, 0.f};
#pragma unroll 4
  for (int k4 = 0; k4 < 128; ++k4) {
    f32x4 w = w4[k4];
#pragma unroll
    for (int rr = 0; rr < 4; ++rr) {
      f32x4 s = s4[(size_t)re[rr] * 128 + k4];
      acc[rr] = fmaf(s.x, w.x, acc[rr]);
      acc[rr] = fmaf(s.y, w.y, acc[rr]);
      acc[rr] = fmaf(s.z, w.z, acc[rr]);
      acc[rr] = fmaf(s.w, w.w, acc[rr]);
    }
  }
#pragma unroll
  for (int rr = 0; rr < 4; ++rr) {
    int r = r0 + rr;
    if (r < 16384) {
      if (j < 50) lc[(size_t)r * 50 + j] = acc[rr] + bias;
      else        cc[(size_t)r * 32 + (j - 50)] = acc[rr] + bias;
    }
  }
}

// ---------------------------------------------------------------------------
// Fold mid->out linear chain: Wq[18][32] = W_out@W_mid, bq = W_out@b_mid+b_out
// ---------------------------------------------------------------------------
__global__ __launch_bounds__(576) void wq_fold(
    const float* __restrict__ W_mid, const float* __restrict__ b_mid,
    const float* __restrict__ W_out, const float* __restrict__ b_out,
    float* __restrict__ wq, float* __restrict__ bq) {
  const int tid = threadIdx.x;
  if (tid < 576) {
    const int a = tid / 32, k = tid % 32;
    float acc = 0.f;
#pragma unroll
    for (int m = 0; m < 64; ++m) acc = fmaf(W_out[a * 64 + m], W_mid[m * 32 + k], acc);
    wq[a * 32 + k] = acc;
  }
  if (tid < 18) {
    float acc = b_out[tid];
#pragma unroll
    for (int m = 0; m < 64; ++m) acc = fmaf(W_out[tid * 64 + m], b_mid[m], acc);
    bq[tid] = acc;
  }
}

// ---------------------------------------------------------------------------
// dp[m][h] = demo_flat[m,:512] · W_comb[h,:512]   (m = (t*B+b)*50+l)
// bf16 MFMA 16x16x32 with hi/lo split (3 products) for ~fp32 accuracy.
// Block: 256 thr = 4 waves x 16 rows; K=512 in 16 chunks, 4-deep prefetch.
// ---------------------------------------------------------------------------
__global__ __launch_bounds__(256) void dp_gemm(const float* __restrict__ demo,
                                               const float* __restrict__ W_comb,
                                               float* __restrict__ dp) {
  __shared__ short frag[2][16][2][64][8];  // [hi/lo][kchunk][ntile][lane][j] = 64 KB
  const int tid = threadIdx.x;
  for (int f = tid; f < 16384; f += 256) {
    int j = f & 7, l = (f >> 3) & 63, nt = (f >> 9) & 1, c = f >> 10;
    int n = nt * 16 + (l & 15);
    int k = c * 32 + ((l >> 4) << 3) + j;
    float v = W_comb[(size_t)n * 1024 + k];
    unsigned u = __float_as_uint(v);
    unsigned hb = u & 0xffff0000u;
    frag[0][c][nt][l][j] = (short)(hb >> 16);
    frag[1][c][nt][l][j] = f2bf_rne(v - __uint_as_float(hb));
  }
  __syncthreads();

  const int wave = tid >> 6, lane = tid & 63;
  const size_t r0 = (size_t)blockIdx.x * 64 + wave * 16;
  const float* arow = demo + (r0 + (lane & 15)) * 512 + ((lane >> 4) << 3);

  f32x4 buf[4][2];
#pragma unroll
  for (int c = 0; c < 4; ++c) {
    buf[c][0] = *(const f32x4*)(arow + c * 32);
    buf[c][1] = *(const f32x4*)(arow + c * 32 + 4);
  }
  f32x4 acc0 = {0.f, 0.f, 0.f, 0.f}, acc1 = {0.f, 0.f, 0.f, 0.f};
#pragma unroll
  for (int c = 0; c < 16; ++c) {
    short8 ahi, alo;
#pragma unroll
    for (int half = 0; half < 2; ++half) {
      f32x4 v4 = buf[c & 3][half];
#pragma unroll
      for (int j = 0; j < 4; ++j) {
        float v = v4[j];
        unsigned u = __float_as_uint(v);
        unsigned hb = u & 0xffff0000u;
        ahi[half * 4 + j] = (short)(hb >> 16);
        alo[half * 4 + j] = f2bf_rne(v - __uint_as_float(hb));
      }
    }
    if (c < 12) {
      buf[c & 3][0] = *(const f32x4*)(arow + (c + 4) * 32);
      buf[c & 3][1] = *(const f32x4*)(arow + (c + 4) * 32 + 4);
    }
    short8 bh0 = *(const short8*)&frag[0][c][0][lane][0];
    short8 bl0 = *(const short8*)&frag[1][c][0][lane][0];
    short8 bh1 = *(const short8*)&frag[0][c][1][lane][0];
    short8 bl1 = *(const short8*)&frag[1][c][1][lane][0];
    acc0 = __builtin_amdgcn_mfma_f32_16x16x32_bf16(ahi, bh0, acc0, 0, 0, 0);
    acc1 = __builtin_amdgcn_mfma_f32_16x16x32_bf16(ahi, bh1, acc1, 0, 0, 0);
    acc0 = __builtin_amdgcn_mfma_f32_16x16x32_bf16(alo, bh0, acc0, 0, 0, 0);
    acc1 = __builtin_amdgcn_mfma_f32_16x16x32_bf16(alo, bh1, acc1, 0, 0, 0);
    acc0 = __builtin_amdgcn_mfma_f32_16x16x32_bf16(ahi, bl0, acc0, 0, 0, 0);
    acc1 = __builtin_amdgcn_mfma_f32_16x16x32_bf16(ahi, bl1, acc1, 0, 0, 0);
  }
  float* drow = dp + r0 * 32;
#pragma unroll
  for (int reg = 0; reg < 4; ++reg) {
    int row = ((lane >> 4) << 2) + reg;
    drow[row * 32 + (lane & 15)] = acc0[reg];
    drow[row * 32 + 16 + (lane & 15)] = acc1[reg];
  }
}

// ---------------------------------------------------------------------------
// Sequential scan: 1 wave per batch element. All small matmuls via readlane
// broadcasts in registers; dp/lc/cc double-buffered in LDS via global_load_lds.
// ---------------------------------------------------------------------------
__global__ __launch_bounds__(64, 1) void seq2(
    const float* __restrict__ h0, const float* __restrict__ c0,
    const float* __restrict__ W_attn,
    const float* __restrict__ W_ih, const float* __restrict__ b_ih,
    const float* __restrict__ W_hh, const float* __restrict__ b_hh,
    const float* __restrict__ ws, float* __restrict__ out) {
  __shared__ alignas(16) float dpb[2][1600];
  __shared__ alignas(16) float lcb[2][64];
  __shared__ alignas(16) float ccb[2][64];
  const int b = blockIdx.x, lane = threadIdx.x, hh = lane & 31;
  const float* lcg = ws + WS_LC;
  const float* ccg = ws + WS_CC;
  const float* wqg = ws + WS_WQ;
  const float* bqg = ws + WS_BQ;
  const float* dpg = ws + WS_DP;

  float wA2[32], wia[32], wib[32], wha[32], whb[32], wq[A_], bq[A_];
  const int l_eff = lane < 50 ? lane : 49;
#pragma unroll
  for (int k = 0; k < 32; ++k) {
    wA2[k] = W_attn[(size_t)l_eff * 544 + 512 + k];
    wia[k] = W_ih[lane * 32 + k];
    wib[k] = W_ih[(64 + lane) * 32 + k];
    wha[k] = W_hh[lane * 32 + k];
    whb[k] = W_hh[(64 + lane) * 32 + k];
  }
#pragma unroll
  for (int a = 0; a < A_; ++a) { wq[a] = wqg[a * 32 + hh]; bq[a] = bqg[a]; }
  const float bga = b_ih[lane] + b_hh[lane];
  const float bgb = b_ih[64 + lane] + b_hh[64 + lane];
  float h = h0[b * 32 + hh], c = c0[b * 32 + hh];

  { // prefetch t=0
    const float* dsrc = dpg + (size_t)b * 1600;
#pragma unroll
    for (int i = 0; i < 6; ++i) glds16(dsrc + i * 256 + lane * 4, &dpb[0][i * 256]);
    glds4(dsrc + 1536 + lane, &dpb[0][1536]);
    glds4(lcg + (size_t)b * 50 + lane, &lcb[0][0]);
    glds4(ccg + (size_t)b * 32 + lane, &ccb[0][0]);
  }

  for (int t = 0; t < T_; ++t) {
    const int p = t & 1, pn = p ^ 1;
    { // prefetch t+1 (last iter reads harmlessly past dp inside the huge ws)
      const size_t rown = (size_t)(t + 1) * B_ + b;
      const float* dsrc = dpg + rown * 1600;
#pragma unroll
      for (int i = 0; i < 6; ++i) glds16(dsrc + i * 256 + lane * 4, &dpb[pn][i * 256]);
      glds4(dsrc + 1536 + lane, &dpb[pn][1536]);
      glds4(lcg + rown * 50 + lane, &lcb[pn][0]);
      glds4(ccg + rown * 32 + lane, &ccb[pn][0]);
    }
    asm volatile("s_waitcnt vmcnt(9)" ::: "memory");  // current step's 9 loads done
    __builtin_amdgcn_sched_barrier(0);

    // logits (lane l<50): lc + h·W_attn[l,512:]
    float lg0 = 0.f, lg1 = 0.f;
#pragma unroll
    for (int k = 0; k < 32; k += 2) {
      lg0 = fmaf(bcast(h, k), wA2[k], lg0);
      lg1 = fmaf(bcast(h, k + 1), wA2[k + 1], lg1);
    }
    const float logit = (lane < 50) ? (lcb[p][lane] + lg0 + lg1) : -1e30f;
    float mx = logit;
#pragma unroll
    for (int off = 32; off; off >>= 1) mx = fmaxf(mx, __shfl_xor(mx, off, 64));
    const float e = (lane < 50) ? expf(logit - mx) : 0.f;
    float se = e;
#pragma unroll
    for (int off = 32; off; off >>= 1) se += __shfl_xor(se, off, 64);
    const float wsm = e / se;

    // x[h] = relu( sum_l w[l]·dp[l,h] + cc[h] )
    float xl0 = 0.f, xl1 = 0.f;
#pragma unroll
    for (int l = 0; l < 50; l += 2) {
      xl0 = fmaf(bcast(wsm, l), dpb[p][l * 32 + hh], xl0);
      xl1 = fmaf(bcast(wsm, l + 1), dpb[p][(l + 1) * 32 + hh], xl1);
    }
    const float x = fmaxf(xl0 + xl1 + ccb[p][hh], 0.f);

    // gates: lane owns rows lane (i|f) and 64+lane (g|o)
    float ga0 = bga, ga1 = 0.f, gb0 = bgb, gb1 = 0.f;
#pragma unroll
    for (int k = 0; k < 32; k += 2) {
      float xv0 = bcast(x, k), hv0 = bcast(h, k);
      float xv1 = bcast(x, k + 1), hv1 = bcast(h, k + 1);
      ga0 = fmaf(xv0, wia[k], ga0);     ga0 = fmaf(hv0, wha[k], ga0);
      ga1 = fmaf(xv1, wia[k + 1], ga1); ga1 = fmaf(hv1, wha[k + 1], ga1);
      gb0 = fmaf(xv0, wib[k], gb0);     gb0 = fmaf(hv0, whb[k], gb0);
      gb1 = fmaf(xv1, wib[k + 1], gb1); gb1 = fmaf(hv1, whb[k + 1], gb1);
    }
    const float ga = ga0 + ga1, gb = gb0 + gb1;
    const float xga = __shfl_xor(ga, 32, 64), xgb = __shfl_xor(gb, 32, 64);
    const bool low = lane < 32;
    const float iv = low ? ga : xga, fv = low ? xga : ga;
    const float gv = low ? gb : xgb, ov = low ? xgb : gb;
    c = sigf(fv) * c + sigf(iv) * tanhf(gv);
    h = sigf(ov) * tanhf(c);

    // q[a] = h·Wq[a,:] + bq[a]  (mid folded away)
    float pq[A_];
#pragma unroll
    for (int a = 0; a < A_; ++a) pq[a] = h * wq[a];
#pragma unroll
    for (int off = 16; off; off >>= 1) {
#pragma unroll
      for (int a = 0; a < A_; ++a) pq[a] += __shfl_xor(pq[a], off, 64);
    }
    if (lane == 0) {
      float* o = out + ((size_t)t * B_ + b) * A_;
#pragma unroll
      for (int a = 0; a < A_; ++a) o[a] = pq[a] + bq[a];
    }
  }
  if (lane < 32) {
    out[(size_t)T_ * B_ * A_ + (size_t)b * H_ + lane] = h;
    out[(size_t)T_ * B_ * A_ + (size_t)B_ * H_ + (size_t)b * H_ + lane] = c;
  }
}

extern "C" void kernel_launch(void* const* d_in, const int* in_sizes, int n_in,
                              void* d_out, int out_size, void* d_ws, size_t ws_size,
                              hipStream_t stream) {
  const float* state  = (const float*)d_in[0];
  const float* demo   = (const float*)d_in[1];
  const float* h0     = (const float*)d_in[2];
  const float* c0     = (const float*)d_in[3];
  const float* W_attn = (const float*)d_in[4];
  const float* b_attn = (const float*)d_in[5];
  const float* W_comb = (const float*)d_in[6];
  const float* b_comb = (const float*)d_in[7];
  const float* W_ih   = (const float*)d_in[8];
  const float* b_ih   = (const float*)d_in[9];
  const float* W_hh   = (const float*)d_in[10];
  const float* b_hh   = (const float*)d_in[11];
  const float* W_mid  = (const float*)d_in[12];
  const float* b_mid  = (const float*)d_in[13];
  const float* W_out  = (const float*)d_in[14];
  const float* b_out  = (const float*)d_in[15];
  float* out = (float*)d_out;
  float* ws  = (float*)d_ws;

  precompute2<<<dim3(683), dim3(512), 0, stream>>>(
      state, W_attn, b_attn, W_comb, b_comb, ws + WS_LC, ws + WS_CC);
  wq_fold<<<dim3(1), dim3(576), 0, stream>>>(
      W_mid, b_mid, W_out, b_out, ws + WS_WQ, ws + WS_BQ);
  dp_gemm<<<dim3(12800), dim3(256), 0, stream>>>(demo, W_comb, ws + WS_DP);
  seq2<<<dim3(256), dim3(64), 0, stream>>>(
      h0, c0, W_attn, W_ih, b_ih, W_hh, b_hh, ws, out);
}

// Round 4
// 609.908 us; speedup vs baseline: 2.1331x; 1.8261x over previous
//
#include <hip/hip_runtime.h>
#include <cstddef>

#define T_ 64
#define B_ 256
#define D_ 512
#define L_ 50
#define A_ 18
#define H_ 32

typedef __attribute__((ext_vector_type(8))) short short8;
typedef __attribute__((ext_vector_type(4))) float f32x4;

// ---- workspace float offsets ----
constexpr size_t WS_LC   = 0;                      // [16384*50]
constexpr size_t WS_CC   = 819200;                 // [16384*32]
constexpr size_t WS_WQ   = 1343488;                // [32*18] transposed W_out@W_mid
constexpr size_t WS_BQ   = 1344064;                // [18]
constexpr size_t WS_HIST = 1344128;                // [B][T][32] h history
constexpr size_t WS_DP   = 1868416;                // [819200*32] dp = demo @ Wc1^T

__device__ __forceinline__ float sigf(float x) { return 1.f / (1.f + expf(-x)); }

__device__ __forceinline__ short f2bf_rne(float f) {
  unsigned u = __float_as_uint(f);
  return (short)((u + 0x7fffu + ((u >> 16) & 1u)) >> 16);
}
__device__ __forceinline__ float bcast(float v, int l) {
  return __int_as_float(__builtin_amdgcn_readlane(__float_as_int(v), l));
}
__device__ __forceinline__ void glds16(const float* g, float* l) {
  __builtin_amdgcn_global_load_lds((const __attribute__((address_space(1))) unsigned*)g,
                                   (__attribute__((address_space(3))) unsigned*)l, 16, 0, 0);
}
__device__ __forceinline__ void glds4(const float* g, float* l) {
  __builtin_amdgcn_global_load_lds((const __attribute__((address_space(1))) unsigned*)g,
                                   (__attribute__((address_space(3))) unsigned*)l, 4, 0, 0);
}

// ---------------------------------------------------------------------------
// lc[r,l] = state[r,:]·W_attn[l,:512] + b_attn[l]   (l<50)
// cc[r,h] = state[r,:]·W_comb[h,512:] + b_comb[h]   (h<32)
// 24 rows staged in LDS per block; thread (j, rg) does 4 rows with one weight row.
// ---------------------------------------------------------------------------
__global__ __launch_bounds__(512) void precompute2(
    const float* __restrict__ state,
    const float* __restrict__ W_attn, const float* __restrict__ b_attn,
    const float* __restrict__ W_comb, const float* __restrict__ b_comb,
    float* __restrict__ lc, float* __restrict__ cc) {
  __shared__ float scur[24 * 512];
  const int tid = threadIdx.x;
  const int r0 = blockIdx.x * 24;
  for (int f = tid; f < 24 * 512; f += 512) {
    int r = r0 + (f >> 9);
    scur[f] = (r < 16384) ? state[(size_t)r * 512 + (f & 511)] : 0.f;
  }
  __syncthreads();
  if (tid >= 492) return;
  const int j = tid % 82, rg = tid / 82;
  const float* wrow = (j < 50) ? (W_attn + (size_t)j * 544)
                               : (W_comb + (size_t)(j - 50) * 1024 + 512);
  const float bias = (j < 50) ? b_attn[j] : b_comb[j - 50];
  const f32x4* w4 = (const f32x4*)wrow;
  const f32x4* s4 = (const f32x4*)scur;
  float acc[4] = {0.f, 0.f, 0.f, 0.f};
#pragma unroll 2
  for (int k4 = 0; k4 < 128; ++k4) {
    f32x4 w = w4[k4];
#pragma unroll
    for (int rr = 0; rr < 4; ++rr) {
      f32x4 s = s4[(rg * 4 + rr) * 128 + k4];
      acc[rr] = fmaf(s.x, w.x, acc[rr]);
      acc[rr] = fmaf(s.y, w.y, acc[rr]);
      acc[rr] = fmaf(s.z, w.z, acc[rr]);
      acc[rr] = fmaf(s.w, w.w, acc[rr]);
    }
  }
#pragma unroll
  for (int rr = 0; rr < 4; ++rr) {
    int r = r0 + rg * 4 + rr;
    if (r < 16384) {
      if (j < 50) lc[(size_t)r * 50 + j] = acc[rr] + bias;
      else        cc[(size_t)r * 32 + (j - 50)] = acc[rr] + bias;
    }
  }
}

// ---------------------------------------------------------------------------
// Wq_t[k][a] = (W_out@W_mid)[a][k]  (transposed for q_kernel), bq = W_out@b_mid+b_out
// ---------------------------------------------------------------------------
__global__ __launch_bounds__(576) void wq_fold(
    const float* __restrict__ W_mid, const float* __restrict__ b_mid,
    const float* __restrict__ W_out, const float* __restrict__ b_out,
    float* __restrict__ wqt, float* __restrict__ bq) {
  const int tid = threadIdx.x;
  if (tid < 576) {
    const int a = tid / 32, k = tid % 32;
    float acc = 0.f;
#pragma unroll
    for (int m = 0; m < 64; ++m) acc = fmaf(W_out[a * 64 + m], W_mid[m * 32 + k], acc);
    wqt[k * 18 + a] = acc;
  }
  if (tid < 18) {
    float acc = b_out[tid];
#pragma unroll
    for (int m = 0; m < 64; ++m) acc = fmaf(W_out[tid * 64 + m], b_mid[m], acc);
    bq[tid] = acc;
  }
}

// ---------------------------------------------------------------------------
// dp[m][h] = demo_flat[m,:512]·W_comb[h,:512]  (m = (t*B+b)*50+l), bf16 3-product.
// 256 persistent blocks x 512 thr (8 waves). LDS: B-frags 64KB (staged once) +
// A double-buffer 2x32KB (128 rows x 64 k, XOR-swizzled via pre-swizzled source).
// Each wave stages its OWN 16 rows -> no K-loop barriers, counted vmcnt(4) only.
// ---------------------------------------------------------------------------
__global__ __launch_bounds__(512, 2) void dp_gemm(const float* __restrict__ demo,
                                                  const float* __restrict__ W_comb,
                                                  float* __restrict__ dp) {
  extern __shared__ char smraw[];
  float* Abuf = (float*)smraw;                    // [2][8192] floats
  short* frag = (short*)(smraw + 65536);          // [2][16][2][64][8] shorts
  const int tid = threadIdx.x;

  for (int f = tid; f < 16384; f += 512) {
    int j = f & 7, l = (f >> 3) & 63, nt = (f >> 9) & 1, c = f >> 10;
    int n = nt * 16 + (l & 15);
    int k = c * 32 + ((l >> 4) << 3) + j;
    float v = W_comb[(size_t)n * 1024 + k];
    unsigned u = __float_as_uint(v);
    unsigned hb = u & 0xffff0000u;
    frag[(((0 * 16 + c) * 2 + nt) * 64 + l) * 8 + j] = (short)(hb >> 16);
    frag[(((1 * 16 + c) * 2 + nt) * 64 + l) * 8 + j] = f2bf_rne(v - __uint_as_float(hb));
  }
  __syncthreads();

  const int wave = tid >> 6, lane = tid & 63;
  const size_t row0 = (size_t)blockIdx.x * 3200;  // 25 tiles x 128 rows per block

  // staging geometry: instr i covers rows wave*16+i*4 .. +3; source pre-swizzled
  int rrl[4], gcol[4];
#pragma unroll
  for (int i = 0; i < 4; ++i) {
    rrl[i] = wave * 16 + i * 4 + (lane >> 4);                      // row in 128-tile
    gcol[i] = ((((lane & 15) * 16) ^ ((rrl[i] & 7) << 4)) >> 2);   // float col in 64-blk
  }

  const int rr = wave * 16 + (lane & 15);   // compute-row for this lane
  const int g = lane >> 4;

  f32x4 acc0 = {0.f, 0.f, 0.f, 0.f}, acc1 = {0.f, 0.f, 0.f, 0.f};

#define STAGE(Q, SLOT)                                                          \
  {                                                                             \
    const int tile_ = (Q) >> 3, kc_ = (Q) & 7;                                  \
    const size_t rbase_ = row0 + (size_t)tile_ * 128;                           \
    float* dst_ = Abuf + (SLOT) * 8192 + wave * 1024;                           \
    _Pragma("unroll")                                                           \
    for (int i = 0; i < 4; ++i) {                                               \
      const float* src_ = demo + (rbase_ + rrl[i]) * 512 + kc_ * 64 + gcol[i];  \
      glds16(src_, dst_ + i * 256);                                             \
    }                                                                           \
  }

  STAGE(0, 0);
  for (int q = 0; q < 200; ++q) {
    const int qn = (q + 1 < 200) ? q + 1 : 199;   // redundant restage keeps vmcnt uniform
    STAGE(qn, (q + 1) & 1);
    asm volatile("s_waitcnt vmcnt(4)" ::: "memory");
    __builtin_amdgcn_sched_barrier(0);
    if ((q & 7) == 0) {
      acc0 = {0.f, 0.f, 0.f, 0.f};
      acc1 = {0.f, 0.f, 0.f, 0.f};
    }
    const char* ab = (const char*)(Abuf + (q & 1) * 8192) + rr * 256;
#pragma unroll
    for (int sub = 0; sub < 2; ++sub) {
      const int b0 = (sub * 128 + g * 32) ^ ((rr & 7) << 4);
      f32x4 a0 = *(const f32x4*)(ab + b0);
      f32x4 a1 = *(const f32x4*)(ab + (b0 ^ 16));
      short8 ahi, alo;
#pragma unroll
      for (int j = 0; j < 4; ++j) {
        float v = a0[j];
        unsigned u = __float_as_uint(v), hb = u & 0xffff0000u;
        ahi[j] = (short)(hb >> 16);
        alo[j] = f2bf_rne(v - __uint_as_float(hb));
        float w = a1[j];
        unsigned u2 = __float_as_uint(w), hb2 = u2 & 0xffff0000u;
        ahi[4 + j] = (short)(hb2 >> 16);
        alo[4 + j] = f2bf_rne(w - __uint_as_float(hb2));
      }
      const int ck = (q & 7) * 2 + sub;
      short8 bh0 = *(const short8*)&frag[(((0 + ck) * 2 + 0) * 64 + lane) * 8];
      short8 bh1 = *(const short8*)&frag[(((0 + ck) * 2 + 1) * 64 + lane) * 8];
      short8 bl0 = *(const short8*)&frag[(((16 + ck) * 2 + 0) * 64 + lane) * 8];
      short8 bl1 = *(const short8*)&frag[(((16 + ck) * 2 + 1) * 64 + lane) * 8];
      acc0 = __builtin_amdgcn_mfma_f32_16x16x32_bf16(ahi, bh0, acc0, 0, 0, 0);
      acc1 = __builtin_amdgcn_mfma_f32_16x16x32_bf16(ahi, bh1, acc1, 0, 0, 0);
      acc0 = __builtin_amdgcn_mfma_f32_16x16x32_bf16(alo, bh0, acc0, 0, 0, 0);
      acc1 = __builtin_amdgcn_mfma_f32_16x16x32_bf16(alo, bh1, acc1, 0, 0, 0);
      acc0 = __builtin_amdgcn_mfma_f32_16x16x32_bf16(ahi, bl0, acc0, 0, 0, 0);
      acc1 = __builtin_amdgcn_mfma_f32_16x16x32_bf16(ahi, bl1, acc1, 0, 0, 0);
    }
    if ((q & 7) == 7) {
      float* drow = dp + (row0 + (size_t)(q >> 3) * 128 + wave * 16) * 32;
#pragma unroll
      for (int reg = 0; reg < 4; ++reg) {
        int r = ((lane >> 4) << 2) + reg;
        drow[r * 32 + (lane & 15)] = acc0[reg];
        drow[r * 32 + 16 + (lane & 15)] = acc1[reg];
      }
    }
  }
#undef STAGE
}

// ---------------------------------------------------------------------------
// Sequential scan: 1 wave per batch element; depth-2 LDS prefetch (vmcnt(18));
// no in-loop global stores (h history kept in LDS, dumped at end).
// ---------------------------------------------------------------------------
__global__ __launch_bounds__(64, 1) void seq2(
    const float* __restrict__ h0, const float* __restrict__ c0,
    const float* __restrict__ W_attn,
    const float* __restrict__ W_ih, const float* __restrict__ b_ih,
    const float* __restrict__ W_hh, const float* __restrict__ b_hh,
    const float* __restrict__ ws, float* __restrict__ histg,
    float* __restrict__ out) {
  __shared__ alignas(16) float dpb[3][1600];
  __shared__ alignas(16) float lcb[3][64];
  __shared__ alignas(16) float ccb[3][64];
  __shared__ alignas(16) float hist[T_ * 32];
  const int b = blockIdx.x, lane = threadIdx.x, hh = lane & 31;
  const float* lcg = ws + WS_LC;
  const float* ccg = ws + WS_CC;
  const float* dpg = ws + WS_DP;

  float wA2[32], wia[32], wib[32], wha[32], whb[32];
  const int l_eff = lane < 50 ? lane : 49;
#pragma unroll
  for (int k = 0; k < 32; ++k) {
    wA2[k] = W_attn[(size_t)l_eff * 544 + 512 + k];
    wia[k] = W_ih[lane * 32 + k];
    wib[k] = W_ih[(64 + lane) * 32 + k];
    wha[k] = W_hh[lane * 32 + k];
    whb[k] = W_hh[(64 + lane) * 32 + k];
  }
  const float bga = b_ih[lane] + b_hh[lane];
  const float bgb = b_ih[64 + lane] + b_hh[64 + lane];
  float h = h0[b * 32 + hh], c = c0[b * 32 + hh];

#pragma unroll
  for (int tt = 0; tt < 2; ++tt) {   // prefetch t=0,1
    const size_t rown = (size_t)tt * B_ + b;
    const float* dsrc = dpg + rown * 1600;
#pragma unroll
    for (int i = 0; i < 6; ++i) glds16(dsrc + i * 256 + lane * 4, &dpb[tt][i * 256]);
    glds4(dsrc + 1536 + lane, &dpb[tt][1536]);
    glds4(lcg + rown * 50 + lane, &lcb[tt][0]);
    glds4(ccg + rown * 32 + lane, &ccb[tt][0]);
  }

  int p = 0;
  for (int t = 0; t < T_; ++t) {
    const int pn = (p >= 1) ? p - 1 : p + 2;      // (t+2)%3
    {
      const size_t rown = (size_t)(t + 2) * B_ + b;  // overreads stay inside ws
      const float* dsrc = dpg + rown * 1600;
#pragma unroll
      for (int i = 0; i < 6; ++i) glds16(dsrc + i * 256 + lane * 4, &dpb[pn][i * 256]);
      glds4(dsrc + 1536 + lane, &dpb[pn][1536]);
      glds4(lcg + rown * 50 + lane, &lcb[pn][0]);
      glds4(ccg + rown * 32 + lane, &ccb[pn][0]);
    }
    asm volatile("s_waitcnt vmcnt(18)" ::: "memory");
    __builtin_amdgcn_sched_barrier(0);

    // logits (lane l<50): lc + h·W_attn[l,512:]
    float lg0 = 0.f, lg1 = 0.f;
#pragma unroll
    for (int k = 0; k < 32; k += 2) {
      lg0 = fmaf(bcast(h, k), wA2[k], lg0);
      lg1 = fmaf(bcast(h, k + 1), wA2[k + 1], lg1);
    }
    const float logit = (lane < 50) ? (lcb[p][lane] + lg0 + lg1) : -1e30f;
    float mx = logit;
#pragma unroll
    for (int off = 32; off; off >>= 1) mx = fmaxf(mx, __shfl_xor(mx, off, 64));
    const float e = (lane < 50) ? expf(logit - mx) : 0.f;
    float se = e;
#pragma unroll
    for (int off = 32; off; off >>= 1) se += __shfl_xor(se, off, 64);
    const float wsm = e / se;

    // x[h] = relu( sum_l w[l]·dp[l,h] + cc[h] )
    float xl0 = 0.f, xl1 = 0.f;
#pragma unroll
    for (int l = 0; l < 50; l += 2) {
      xl0 = fmaf(bcast(wsm, l), dpb[p][l * 32 + hh], xl0);
      xl1 = fmaf(bcast(wsm, l + 1), dpb[p][(l + 1) * 32 + hh], xl1);
    }
    const float x = fmaxf(xl0 + xl1 + ccb[p][hh], 0.f);

    // gates: lane owns rows lane (i|f) and 64+lane (g|o)
    float ga0 = bga, ga1 = 0.f, gb0 = bgb, gb1 = 0.f;
#pragma unroll
    for (int k = 0; k < 32; k += 2) {
      float xv0 = bcast(x, k), hv0 = bcast(h, k);
      float xv1 = bcast(x, k + 1), hv1 = bcast(h, k + 1);
      ga0 = fmaf(xv0, wia[k], ga0);     ga0 = fmaf(hv0, wha[k], ga0);
      ga1 = fmaf(xv1, wia[k + 1], ga1); ga1 = fmaf(hv1, wha[k + 1], ga1);
      gb0 = fmaf(xv0, wib[k], gb0);     gb0 = fmaf(hv0, whb[k], gb0);
      gb1 = fmaf(xv1, wib[k + 1], gb1); gb1 = fmaf(hv1, whb[k + 1], gb1);
    }
    const float ga = ga0 + ga1, gb = gb0 + gb1;
    const float xga = __shfl_xor(ga, 32, 64), xgb = __shfl_xor(gb, 32, 64);
    const bool low = lane < 32;
    const float iv = low ? ga : xga, fv = low ? xga : ga;
    const float gv = low ? gb : xgb, ov = low ? xgb : gb;
    c = sigf(fv) * c + sigf(iv) * tanhf(gv);
    h = sigf(ov) * tanhf(c);
    if (lane < 32) hist[t * 32 + hh] = h;

    p = (p + 1 == 3) ? 0 : p + 1;
  }

  // dump h history + final h,c
  for (int f = lane; f < 512; f += 64)
    ((f32x4*)(histg + (size_t)b * 2048))[f] = ((const f32x4*)hist)[f];
  if (lane < 32) {
    out[(size_t)T_ * B_ * A_ + (size_t)b * H_ + lane] = h;
    out[(size_t)T_ * B_ * A_ + (size_t)B_ * H_ + (size_t)b * H_ + lane] = c;
  }
}

// ---------------------------------------------------------------------------
// q[t,b,a] = hist[b,t,:]·Wq_t[:,a] + bq[a] — one block per b.
// ---------------------------------------------------------------------------
__global__ __launch_bounds__(256) void q_kernel(
    const float* __restrict__ histg, const float* __restrict__ wqt,
    const float* __restrict__ bq, float* __restrict__ out) {
  __shared__ float sh[64 * 33];   // padded: bank-conflict-free
  __shared__ float swq[576];
  __shared__ float sbq[18];
  const int b = blockIdx.x, tid = threadIdx.x;
  for (int f = tid; f < 2048; f += 256) {
    int t = f >> 5, k = f & 31;
    sh[t * 33 + k] = histg[(size_t)b * 2048 + f];
  }
  for (int f = tid; f < 576; f += 256) swq[f] = wqt[f];   // FIX: was if(tid<576) with 256 threads
  if (tid < 18) sbq[tid] = bq[tid];
  __syncthreads();
  for (int idx = tid; idx < 1152; idx += 256) {
    int t = idx / 18, a = idx - t * 18;
    float acc = sbq[a];
#pragma unroll
    for (int k = 0; k < 32; ++k) acc = fmaf(sh[t * 33 + k], swq[k * 18 + a], acc);
    out[((size_t)t * B_ + b) * A_ + a] = acc;
  }
}

extern "C" void kernel_launch(void* const* d_in, const int* in_sizes, int n_in,
                              void* d_out, int out_size, void* d_ws, size_t ws_size,
                              hipStream_t stream) {
  const float* state  = (const float*)d_in[0];
  const float* demo   = (const float*)d_in[1];
  const float* h0     = (const float*)d_in[2];
  const float* c0     = (const float*)d_in[3];
  const float* W_attn = (const float*)d_in[4];
  const float* b_attn = (const float*)d_in[5];
  const float* W_comb = (const float*)d_in[6];
  const float* b_comb = (const float*)d_in[7];
  const float* W_ih   = (const float*)d_in[8];
  const float* b_ih   = (const float*)d_in[9];
  const float* W_hh   = (const float*)d_in[10];
  const float* b_hh   = (const float*)d_in[11];
  const float* W_mid  = (const float*)d_in[12];
  const float* b_mid  = (const float*)d_in[13];
  const float* W_out  = (const float*)d_in[14];
  const float* b_out  = (const float*)d_in[15];
  float* out = (float*)d_out;
  float* ws  = (float*)d_ws;

  wq_fold<<<dim3(1), dim3(576), 0, stream>>>(
      W_mid, b_mid, W_out, b_out, ws + WS_WQ, ws + WS_BQ);
  precompute2<<<dim3(683), dim3(512), 0, stream>>>(
      state, W_attn, b_attn, W_comb, b_comb, ws + WS_LC, ws + WS_CC);

  constexpr int dp_smem = 131072;  // 64KB A dbuf + 64KB B frags
  (void)hipFuncSetAttribute(reinterpret_cast<const void*>(dp_gemm),
                            hipFuncAttributeMaxDynamicSharedMemorySize, dp_smem);
  dp_gemm<<<dim3(256), dim3(512), dp_smem, stream>>>(demo, W_comb, ws + WS_DP);

  seq2<<<dim3(256), dim3(64), 0, stream>>>(
      h0, c0, W_attn, W_ih, b_ih, W_hh, b_hh, ws, ws + WS_HIST, out);
  q_kernel<<<dim3(256), dim3(256), 0, stream>>>(
      ws + WS_HIST, ws + WS_WQ, ws + WS_BQ, out);
}

// Round 5
// 550.378 us; speedup vs baseline: 2.3638x; 1.1082x over previous
//
#include <hip/hip_runtime.h>
#include <cstddef>

#define T_ 64
#define B_ 256
#define D_ 512
#define L_ 50
#define A_ 18
#define H_ 32

typedef __attribute__((ext_vector_type(8))) short short8;
typedef __attribute__((ext_vector_type(4))) float f32x4;

// ---- workspace float offsets ----
constexpr size_t WS_LC = 0;              // [16384*50]
constexpr size_t WS_CC = 819200;         // [16384*32]
constexpr size_t WS_DP = 1868416;        // [819200*32] dp = demo @ Wc1^T

__device__ __forceinline__ float sigf(float x) { return 1.f / (1.f + expf(-x)); }

__device__ __forceinline__ short f2bf_rne(float f) {
  unsigned u = __float_as_uint(f);
  return (short)((u + 0x7fffu + ((u >> 16) & 1u)) >> 16);
}
__device__ __forceinline__ float bcast(float v, int l) {
  return __int_as_float(__builtin_amdgcn_readlane(__float_as_int(v), l));
}
__device__ __forceinline__ void glds16(const float* g, float* l) {
  __builtin_amdgcn_global_load_lds((const __attribute__((address_space(1))) unsigned*)g,
                                   (__attribute__((address_space(3))) unsigned*)l, 16, 0, 0);
}
__device__ __forceinline__ void glds4(const float* g, float* l) {
  __builtin_amdgcn_global_load_lds((const __attribute__((address_space(1))) unsigned*)g,
                                   (__attribute__((address_space(3))) unsigned*)l, 4, 0, 0);
}

// ---------------------------------------------------------------------------
// precompute3: MFMA GEMM  C[16384][96] = state[16384][512] . B[512][96]
//   B[k][n] = W_attn[n][k] (n<50) | W_comb[n-50][512+k] (50<=n<82) | 0 (pad)
//   lc[r][n] = C + b_attn ; cc[r][n-50] = C + b_comb
// 256 blocks x 256 thr (4 waves x 16 rows = 64 rows). K-outer staging of B
// (4 kchunks resident), wave-private glds A double-buffer, XOR-swizzled.
// ---------------------------------------------------------------------------
__global__ __launch_bounds__(256) void precompute3(
    const float* __restrict__ state,
    const float* __restrict__ W_attn, const float* __restrict__ b_attn,
    const float* __restrict__ W_comb, const float* __restrict__ b_comb,
    float* __restrict__ lc, float* __restrict__ cc) {
  extern __shared__ char pm3[];
  float* As = (float*)pm3;                 // [2 slots][4 waves][512] = 16 KB
  short* Bf = (short*)(pm3 + 16384);       // [2 hi/lo][4 kc][6 nt][64][8] = 48 KB
  const int tid = threadIdx.x;
  const int wave = tid >> 6, lane = tid & 63;
  const int r0 = blockIdx.x * 64;

  // A staging geometry (pre-swizzled source), per glds instr: 8 rows x 8 blocks
  const int srow = lane >> 3;
  const int scol = (((lane & 7) * 16) ^ (srow << 4)) >> 2;  // float offset
  // compute-read geometry
  const int crow = lane & 15, g = lane >> 4;
  const int cb0 = (g * 32) ^ ((crow & 7) << 4);

  f32x4 acc[6];
#pragma unroll
  for (int nt = 0; nt < 6; ++nt) acc[nt] = {0.f, 0.f, 0.f, 0.f};

#define STAGE_A(KI, SLOT)                                                       \
  {                                                                             \
    float* dst_ = As + ((SLOT) * 4 + wave) * 512;                               \
    _Pragma("unroll")                                                           \
    for (int i_ = 0; i_ < 2; ++i_) {                                            \
      const float* src_ = state +                                               \
          (size_t)(r0 + wave * 16 + i_ * 8 + srow) * 512 + (KI) * 32 + scol;    \
      glds16(src_, dst_ + i_ * 256);                                            \
    }                                                                           \
  }

  auto stageB = [&](int ko) {
#pragma unroll
    for (int it = 0; it < 6; ++it) {
      int u = tid + it * 256;                 // 0..1535
      int l = u & 63;
      int nt = (u >> 6) % 6;
      int c = u / 384;
      int n = nt * 16 + (l & 15);
      int kb = ko * 128 + c * 32 + ((l >> 4) << 3);
      f32x4 v0 = {0.f, 0.f, 0.f, 0.f}, v1 = {0.f, 0.f, 0.f, 0.f};
      if (n < 50) {
        const f32x4* s = (const f32x4*)(W_attn + (size_t)n * 544 + kb);
        v0 = s[0]; v1 = s[1];
      } else if (n < 82) {
        const f32x4* s = (const f32x4*)(W_comb + (size_t)(n - 50) * 1024 + 512 + kb);
        v0 = s[0]; v1 = s[1];
      }
      short8 hi, lo;
#pragma unroll
      for (int j = 0; j < 4; ++j) {
        unsigned ua = __float_as_uint(v0[j]), ha = ua & 0xffff0000u;
        hi[j] = (short)(ha >> 16);
        lo[j] = f2bf_rne(v0[j] - __uint_as_float(ha));
        unsigned ub = __float_as_uint(v1[j]), hb = ub & 0xffff0000u;
        hi[4 + j] = (short)(hb >> 16);
        lo[4 + j] = f2bf_rne(v1[j] - __uint_as_float(hb));
      }
      *(short8*)&Bf[(((0 * 4 + c) * 6 + nt) * 64 + l) * 8] = hi;
      *(short8*)&Bf[(((1 * 4 + c) * 6 + nt) * 64 + l) * 8] = lo;
    }
  };

  STAGE_A(0, 0);
  stageB(0);
  asm volatile("s_waitcnt lgkmcnt(0)" ::: "memory");
  __builtin_amdgcn_s_barrier();

  for (int ko = 0; ko < 4; ++ko) {
    if (ko > 0) {
      __builtin_amdgcn_s_barrier();           // all waves done reading old B
      stageB(ko);
      asm volatile("s_waitcnt lgkmcnt(0)" ::: "memory");
      __builtin_amdgcn_s_barrier();
    }
#pragma unroll
    for (int c = 0; c < 4; ++c) {
      const int ki = ko * 4 + c;
      if (ki < 15) {
        STAGE_A(ki + 1, (ki + 1) & 1);
        asm volatile("s_waitcnt vmcnt(2)" ::: "memory");
      } else {
        asm volatile("s_waitcnt vmcnt(0)" ::: "memory");
      }
      __builtin_amdgcn_sched_barrier(0);
      const char* ab = (const char*)(As + ((ki & 1) * 4 + wave) * 512) + crow * 128;
      f32x4 a0 = *(const f32x4*)(ab + cb0);
      f32x4 a1 = *(const f32x4*)(ab + (cb0 ^ 16));
      short8 ahi, alo;
#pragma unroll
      for (int j = 0; j < 4; ++j) {
        unsigned ua = __float_as_uint(a0[j]), ha = ua & 0xffff0000u;
        ahi[j] = (short)(ha >> 16);
        alo[j] = f2bf_rne(a0[j] - __uint_as_float(ha));
        unsigned ub = __float_as_uint(a1[j]), hb = ub & 0xffff0000u;
        ahi[4 + j] = (short)(hb >> 16);
        alo[4 + j] = f2bf_rne(a1[j] - __uint_as_float(hb));
      }
#pragma unroll
      for (int nt = 0; nt < 6; ++nt) {
        short8 bh = *(const short8*)&Bf[(((0 * 4 + c) * 6 + nt) * 64 + lane) * 8];
        short8 bl = *(const short8*)&Bf[(((1 * 4 + c) * 6 + nt) * 64 + lane) * 8];
        acc[nt] = __builtin_amdgcn_mfma_f32_16x16x32_bf16(ahi, bh, acc[nt], 0, 0, 0);
        acc[nt] = __builtin_amdgcn_mfma_f32_16x16x32_bf16(alo, bh, acc[nt], 0, 0, 0);
        acc[nt] = __builtin_amdgcn_mfma_f32_16x16x32_bf16(ahi, bl, acc[nt], 0, 0, 0);
      }
    }
  }
#undef STAGE_A

#pragma unroll
  for (int nt = 0; nt < 6; ++nt) {
    const int n = nt * 16 + crow;
    float bias = 0.f;
    if (n < 50) bias = b_attn[n];
    else if (n < 82) bias = b_comb[n - 50];
#pragma unroll
    for (int reg = 0; reg < 4; ++reg) {
      const int r = r0 + wave * 16 + (g << 2) + reg;
      const float vv = acc[nt][reg] + bias;
      if (n < 50) lc[(size_t)r * 50 + n] = vv;
      else if (n < 82) cc[(size_t)r * 32 + (n - 50)] = vv;
    }
  }
}

// ---------------------------------------------------------------------------
// dp[m][h] = demo_flat[m,:512]·W_comb[h,:512]  (m=(t*B+b)*50+l), bf16 3-product.
// 256 blocks x 512 thr. LDS 160KB: B-frags 64KB + A 3-slot ring 96KB.
// Wave-private staging, no K-loop barriers; store-aware counted vmcnt.
// ---------------------------------------------------------------------------
__global__ __launch_bounds__(512, 2) void dp_gemm(const float* __restrict__ demo,
                                                  const float* __restrict__ W_comb,
                                                  float* __restrict__ dp) {
  extern __shared__ char smraw[];
  float* Abuf = (float*)smraw;                    // [3][8192] floats = 96 KB
  short* frag = (short*)(smraw + 98304);          // [2][16][2][64][8] = 64 KB
  const int tid = threadIdx.x;

  for (int f = tid; f < 16384; f += 512) {
    int j = f & 7, l = (f >> 3) & 63, nt = (f >> 9) & 1, c = f >> 10;
    int n = nt * 16 + (l & 15);
    int k = c * 32 + ((l >> 4) << 3) + j;
    float v = W_comb[(size_t)n * 1024 + k];
    unsigned u = __float_as_uint(v);
    unsigned hb = u & 0xffff0000u;
    frag[(((0 * 16 + c) * 2 + nt) * 64 + l) * 8 + j] = (short)(hb >> 16);
    frag[(((1 * 16 + c) * 2 + nt) * 64 + l) * 8 + j] = f2bf_rne(v - __uint_as_float(hb));
  }
  __syncthreads();

  const int wave = tid >> 6, lane = tid & 63;
  const size_t row0 = (size_t)blockIdx.x * 3200;  // 25 tiles x 128 rows

  int rrl[4], gcol[4];
#pragma unroll
  for (int i = 0; i < 4; ++i) {
    rrl[i] = wave * 16 + i * 4 + (lane >> 4);
    gcol[i] = ((((lane & 15) * 16) ^ ((rrl[i] & 7) << 4)) >> 2);
  }
  const int rr = wave * 16 + (lane & 15);
  const int g = lane >> 4;

  f32x4 acc0 = {0.f, 0.f, 0.f, 0.f}, acc1 = {0.f, 0.f, 0.f, 0.f};

#define STAGE(Q, SLOT)                                                          \
  {                                                                             \
    const int tile_ = (Q) >> 3, kc_ = (Q) & 7;                                  \
    const size_t rbase_ = row0 + (size_t)tile_ * 128;                           \
    float* dst_ = Abuf + (SLOT) * 8192 + wave * 1024;                           \
    _Pragma("unroll")                                                           \
    for (int i = 0; i < 4; ++i) {                                               \
      const float* src_ = demo + (rbase_ + rrl[i]) * 512 + kc_ * 64 + gcol[i];  \
      glds16(src_, dst_ + i * 256);                                             \
    }                                                                           \
  }

  STAGE(0, 0);
  STAGE(1, 1);
  for (int q = 0; q < 200; ++q) {
    const int q2 = (q + 2 < 200) ? q + 2 : 199;   // clamped restage, uniform count
    STAGE(q2, (q + 2) % 3);
    if (q >= 8 && (q & 7) <= 1) {
      asm volatile("s_waitcnt vmcnt(16)" ::: "memory");   // stores may be in flight
    } else {
      asm volatile("s_waitcnt vmcnt(8)" ::: "memory");
    }
    __builtin_amdgcn_sched_barrier(0);
    if ((q & 7) == 0) {
      acc0 = {0.f, 0.f, 0.f, 0.f};
      acc1 = {0.f, 0.f, 0.f, 0.f};
    }
    const char* ab = (const char*)(Abuf + (q % 3) * 8192) + rr * 256;
#pragma unroll
    for (int sub = 0; sub < 2; ++sub) {
      const int b0 = (sub * 128 + g * 32) ^ ((rr & 7) << 4);
      f32x4 a0 = *(const f32x4*)(ab + b0);
      f32x4 a1 = *(const f32x4*)(ab + (b0 ^ 16));
      short8 ahi, alo;
#pragma unroll
      for (int j = 0; j < 4; ++j) {
        float v = a0[j];
        unsigned u = __float_as_uint(v), hb = u & 0xffff0000u;
        ahi[j] = (short)(hb >> 16);
        alo[j] = f2bf_rne(v - __uint_as_float(hb));
        float w = a1[j];
        unsigned u2 = __float_as_uint(w), hb2 = u2 & 0xffff0000u;
        ahi[4 + j] = (short)(hb2 >> 16);
        alo[4 + j] = f2bf_rne(w - __uint_as_float(hb2));
      }
      const int ck = (q & 7) * 2 + sub;
      short8 bh0 = *(const short8*)&frag[(((0 + ck) * 2 + 0) * 64 + lane) * 8];
      short8 bh1 = *(const short8*)&frag[(((0 + ck) * 2 + 1) * 64 + lane) * 8];
      short8 bl0 = *(const short8*)&frag[(((16 + ck) * 2 + 0) * 64 + lane) * 8];
      short8 bl1 = *(const short8*)&frag[(((16 + ck) * 2 + 1) * 64 + lane) * 8];
      acc0 = __builtin_amdgcn_mfma_f32_16x16x32_bf16(ahi, bh0, acc0, 0, 0, 0);
      acc1 = __builtin_amdgcn_mfma_f32_16x16x32_bf16(ahi, bh1, acc1, 0, 0, 0);
      acc0 = __builtin_amdgcn_mfma_f32_16x16x32_bf16(alo, bh0, acc0, 0, 0, 0);
      acc1 = __builtin_amdgcn_mfma_f32_16x16x32_bf16(alo, bh1, acc1, 0, 0, 0);
      acc0 = __builtin_amdgcn_mfma_f32_16x16x32_bf16(ahi, bl0, acc0, 0, 0, 0);
      acc1 = __builtin_amdgcn_mfma_f32_16x16x32_bf16(ahi, bl1, acc1, 0, 0, 0);
    }
    if ((q & 7) == 7) {
      float* drow = dp + (row0 + (size_t)(q >> 3) * 128 + wave * 16) * 32;
#pragma unroll
      for (int reg = 0; reg < 4; ++reg) {
        int r = ((lane >> 4) << 2) + reg;
        drow[r * 32 + (lane & 15)] = acc0[reg];
        drow[r * 32 + 16 + (lane & 15)] = acc1[reg];
      }
    }
  }
#undef STAGE
}

// ---------------------------------------------------------------------------
// seq3: 1 wave per batch element; depth-2 LDS prefetch; wq-fold and q-output
// fused in (hist stays in LDS, no extra kernels / global round-trip).
// ---------------------------------------------------------------------------
__global__ __launch_bounds__(64, 1) void seq3(
    const float* __restrict__ h0, const float* __restrict__ c0,
    const float* __restrict__ W_attn,
    const float* __restrict__ W_ih, const float* __restrict__ b_ih,
    const float* __restrict__ W_hh, const float* __restrict__ b_hh,
    const float* __restrict__ W_mid, const float* __restrict__ b_mid,
    const float* __restrict__ W_out, const float* __restrict__ b_out,
    const float* __restrict__ ws, float* __restrict__ out) {
  __shared__ alignas(16) float dpb[3][1600];
  __shared__ alignas(16) float lcb[3][64];
  __shared__ alignas(16) float ccb[3][64];
  __shared__ alignas(16) float hist[T_ * 33];   // padded: conflict-free q-phase
  __shared__ float swq[576];                    // (W_out@W_mid)^T  [k][a]
  __shared__ float sbq[20];
  const int b = blockIdx.x, lane = threadIdx.x, hh = lane & 31;
  const float* lcg = ws + WS_LC;
  const float* ccg = ws + WS_CC;
  const float* dpg = ws + WS_DP;

  float wA2[32], wia[32], wib[32], wha[32], whb[32];
  const int l_eff = lane < 50 ? lane : 49;
#pragma unroll
  for (int k = 0; k < 32; ++k) {
    wA2[k] = W_attn[(size_t)l_eff * 544 + 512 + k];
    wia[k] = W_ih[lane * 32 + k];
    wib[k] = W_ih[(64 + lane) * 32 + k];
    wha[k] = W_hh[lane * 32 + k];
    whb[k] = W_hh[(64 + lane) * 32 + k];
  }
  const float bga = b_ih[lane] + b_hh[lane];
  const float bgb = b_ih[64 + lane] + b_hh[64 + lane];
  float h = h0[b * 32 + hh], c = c0[b * 32 + hh];

#pragma unroll
  for (int tt = 0; tt < 2; ++tt) {   // prefetch t=0,1
    const size_t rown = (size_t)tt * B_ + b;
    const float* dsrc = dpg + rown * 1600;
#pragma unroll
    for (int i = 0; i < 6; ++i) glds16(dsrc + i * 256 + lane * 4, &dpb[tt][i * 256]);
    glds4(dsrc + 1536 + lane, &dpb[tt][1536]);
    glds4(lcg + rown * 50 + lane, &lcb[tt][0]);
    glds4(ccg + rown * 32 + lane, &ccb[tt][0]);
  }

  // fold Wq = W_out@W_mid (stored [k][a]) + bq while prefetch is in flight
  for (int idx = lane; idx < 576; idx += 64) {
    int a = idx >> 5, k = idx & 31;
    float acc = 0.f;
#pragma unroll
    for (int m = 0; m < 64; ++m) acc = fmaf(W_out[a * 64 + m], W_mid[m * 32 + k], acc);
    swq[k * 18 + a] = acc;
  }
  if (lane < 18) {
    float acc = b_out[lane];
#pragma unroll
    for (int m = 0; m < 64; ++m) acc = fmaf(W_out[lane * 64 + m], b_mid[m], acc);
    sbq[lane] = acc;
  }

  int p = 0;
  for (int t = 0; t < T_; ++t) {
    const int pn = (p >= 1) ? p - 1 : p + 2;      // (t+2)%3
    {
      const size_t rown = (size_t)(t + 2) * B_ + b;  // overreads stay inside ws
      const float* dsrc = dpg + rown * 1600;
#pragma unroll
      for (int i = 0; i < 6; ++i) glds16(dsrc + i * 256 + lane * 4, &dpb[pn][i * 256]);
      glds4(dsrc + 1536 + lane, &dpb[pn][1536]);
      glds4(lcg + rown * 50 + lane, &lcb[pn][0]);
      glds4(ccg + rown * 32 + lane, &ccb[pn][0]);
    }
    asm volatile("s_waitcnt vmcnt(18)" ::: "memory");
    __builtin_amdgcn_sched_barrier(0);

    // logits (lane l<50): lc + h·W_attn[l,512:]
    float lg0 = 0.f, lg1 = 0.f;
#pragma unroll
    for (int k = 0; k < 32; k += 2) {
      lg0 = fmaf(bcast(h, k), wA2[k], lg0);
      lg1 = fmaf(bcast(h, k + 1), wA2[k + 1], lg1);
    }
    const float logit = (lane < 50) ? (lcb[p][lane] + lg0 + lg1) : -1e30f;
    float mx = logit;
#pragma unroll
    for (int off = 32; off; off >>= 1) mx = fmaxf(mx, __shfl_xor(mx, off, 64));
    const float e = (lane < 50) ? expf(logit - mx) : 0.f;
    float se = e;
#pragma unroll
    for (int off = 32; off; off >>= 1) se += __shfl_xor(se, off, 64);
    const float wsm = e / se;

    // x[h] = relu( sum_l w[l]·dp[l,h] + cc[h] )
    float xl0 = 0.f, xl1 = 0.f;
#pragma unroll
    for (int l = 0; l < 50; l += 2) {
      xl0 = fmaf(bcast(wsm, l), dpb[p][l * 32 + hh], xl0);
      xl1 = fmaf(bcast(wsm, l + 1), dpb[p][(l + 1) * 32 + hh], xl1);
    }
    const float x = fmaxf(xl0 + xl1 + ccb[p][hh], 0.f);

    // gates
    float ga0 = bga, ga1 = 0.f, gb0 = bgb, gb1 = 0.f;
#pragma unroll
    for (int k = 0; k < 32; k += 2) {
      float xv0 = bcast(x, k), hv0 = bcast(h, k);
      float xv1 = bcast(x, k + 1), hv1 = bcast(h, k + 1);
      ga0 = fmaf(xv0, wia[k], ga0);     ga0 = fmaf(hv0, wha[k], ga0);
      ga1 = fmaf(xv1, wia[k + 1], ga1); ga1 = fmaf(hv1, wha[k + 1], ga1);
      gb0 = fmaf(xv0, wib[k], gb0);     gb0 = fmaf(hv0, whb[k], gb0);
      gb1 = fmaf(xv1, wib[k + 1], gb1); gb1 = fmaf(hv1, whb[k + 1], gb1);
    }
    const float ga = ga0 + ga1, gb = gb0 + gb1;
    const float xga = __shfl_xor(ga, 32, 64), xgb = __shfl_xor(gb, 32, 64);
    const bool low = lane < 32;
    const float iv = low ? ga : xga, fv = low ? xga : ga;
    const float gv = low ? gb : xgb, ov = low ? xgb : gb;
    c = sigf(fv) * c + sigf(iv) * tanhf(gv);
    h = sigf(ov) * tanhf(c);
    if (lane < 32) hist[t * 33 + hh] = h;

    p = (p + 1 == 3) ? 0 : p + 1;
  }

  // q[t,a] = hist[t,:]·Wq[:,a] + bq[a]
  for (int idx = lane; idx < T_ * A_; idx += 64) {
    int t = idx / A_, a = idx - t * A_;
    float acc = sbq[a];
#pragma unroll
    for (int k = 0; k < 32; ++k) acc = fmaf(hist[t * 33 + k], swq[k * 18 + a], acc);
    out[((size_t)t * B_ + b) * A_ + a] = acc;
  }
  if (lane < 32) {
    out[(size_t)T_ * B_ * A_ + (size_t)b * H_ + lane] = h;
    out[(size_t)T_ * B_ * A_ + (size_t)B_ * H_ + (size_t)b * H_ + lane] = c;
  }
}

extern "C" void kernel_launch(void* const* d_in, const int* in_sizes, int n_in,
                              void* d_out, int out_size, void* d_ws, size_t ws_size,
                              hipStream_t stream) {
  const float* state  = (const float*)d_in[0];
  const float* demo   = (const float*)d_in[1];
  const float* h0     = (const float*)d_in[2];
  const float* c0     = (const float*)d_in[3];
  const float* W_attn = (const float*)d_in[4];
  const float* b_attn = (const float*)d_in[5];
  const float* W_comb = (const float*)d_in[6];
  const float* b_comb = (const float*)d_in[7];
  const float* W_ih   = (const float*)d_in[8];
  const float* b_ih   = (const float*)d_in[9];
  const float* W_hh   = (const float*)d_in[10];
  const float* b_hh   = (const float*)d_in[11];
  const float* W_mid  = (const float*)d_in[12];
  const float* b_mid  = (const float*)d_in[13];
  const float* W_out  = (const float*)d_in[14];
  const float* b_out  = (const float*)d_in[15];
  float* out = (float*)d_out;
  float* ws  = (float*)d_ws;

  constexpr int pm3_smem = 65536;          // 16 KB A + 48 KB B-frags
  (void)hipFuncSetAttribute(reinterpret_cast<const void*>(precompute3),
                            hipFuncAttributeMaxDynamicSharedMemorySize, pm3_smem);
  precompute3<<<dim3(256), dim3(256), pm3_smem, stream>>>(
      state, W_attn, b_attn, W_comb, b_comb, ws + WS_LC, ws + WS_CC);

  constexpr int dp_smem = 163840;          // 96 KB A ring + 64 KB B-frags
  (void)hipFuncSetAttribute(reinterpret_cast<const void*>(dp_gemm),
                            hipFuncAttributeMaxDynamicSharedMemorySize, dp_smem);
  dp_gemm<<<dim3(256), dim3(512), dp_smem, stream>>>(demo, W_comb, ws + WS_DP);

  seq3<<<dim3(256), dim3(64), 0, stream>>>(
      h0, c0, W_attn, W_ih, b_ih, W_hh, b_hh,
      W_mid, b_mid, W_out, b_out, ws, out);
}